// Round 2
// baseline (517.230 us; speedup 1.0000x reference)
//
#include <hip/hip_runtime.h>
#include <stdint.h>

typedef __attribute__((ext_vector_type(8))) short short8;
typedef __attribute__((ext_vector_type(4))) float floatx4;

#define B_DIM 8192
#define K_DIM 2048
#define N_DIM 2048

// round-to-nearest-even fp32 -> bf16
__device__ __forceinline__ unsigned short f2bf(float f) {
    union { float f; unsigned u; } v; v.f = f;
    unsigned r = v.u + 0x7fffu + ((v.u >> 16) & 1u);
    return (unsigned short)(r >> 16);
}

__device__ __forceinline__ void gld_lds16(const void* g, void* l) {
    __builtin_amdgcn_global_load_lds(
        (const __attribute__((address_space(1))) void*)g,
        (__attribute__((address_space(3))) void*)l, 16, 0, 0);
}

// ---------------- prepass 1: X -> Xb (bf16), Lb = bf16(log(|x|+eps)) ----------------
__global__ __launch_bounds__(256) void prep_x(const float4* __restrict__ X4,
                                              ushort* __restrict__ Xb,
                                              ushort* __restrict__ Lb) {
    int i = blockIdx.x * 256 + threadIdx.x;
    float4 v = X4[i];
    ushort4 xb, lb;
    xb.x = f2bf(v.x); xb.y = f2bf(v.y); xb.z = f2bf(v.z); xb.w = f2bf(v.w);
    lb.x = f2bf(__logf(fabsf(v.x) + 1e-7f));
    lb.y = f2bf(__logf(fabsf(v.y) + 1e-7f));
    lb.z = f2bf(__logf(fabsf(v.z) + 1e-7f));
    lb.w = f2bf(__logf(fabsf(v.w) + 1e-7f));
    *(ushort4*)(Xb + (size_t)i * 4) = xb;
    *(ushort4*)(Lb + (size_t)i * 4) = lb;
}

// ---------------- prepass 2: Wt[n][k] = bf16(tanh(Wh)*sigmoid(Mh)), Gt[n][k] = bf16(gate) ----
__global__ __launch_bounds__(256) void prep_wg(const float* __restrict__ Wh,
                                               const float* __restrict__ Mh,
                                               const float* __restrict__ Gf,
                                               ushort* __restrict__ Wt,
                                               ushort* __restrict__ Gt) {
    __shared__ float tw[32][33];
    __shared__ float tg[32][33];
    const int k0 = blockIdx.y * 32, n0 = blockIdx.x * 32;
    const int tx = threadIdx.x, ty = threadIdx.y;  // 32 x 8
#pragma unroll
    for (int i = 0; i < 4; i++) {
        int k = k0 + ty + i * 8;
        int n = n0 + tx;
        size_t idx = (size_t)k * N_DIM + n;
        float wh = Wh[idx], mh = Mh[idx];
        tw[ty + i * 8][tx] = tanhf(wh) * (1.f / (1.f + __expf(-mh)));
        tg[ty + i * 8][tx] = Gf[idx];
    }
    __syncthreads();
#pragma unroll
    for (int i = 0; i < 4; i++) {
        int n = n0 + ty + i * 8;
        int k = k0 + tx;
        Wt[(size_t)n * K_DIM + k] = f2bf(tw[tx][ty + i * 8]);
        Gt[(size_t)n * K_DIM + k] = f2bf(tg[tx][ty + i * 8]);
    }
}

// ---------------- fused GEMM: a = Xb@Wt^T, lm = Lb@Wt^T, gl = Xb@Gt^T ----------------
// out = sigmoid(gl)*a + (1-sigmoid(gl))*exp(lm)
// 128x128 block tile, 4 waves (2x2), 64x64 per wave per acc set, BK=32.
// 3 accumulator sets (192 AGPR) + frags — fits unified 512-reg file, no spill.
__global__ __launch_bounds__(256, 1) void gemm_fused(const ushort* __restrict__ Xb,
                                                     const ushort* __restrict__ Lb,
                                                     const ushort* __restrict__ Wt,
                                                     const ushort* __restrict__ Gt,
                                                     float* __restrict__ out) {
    __shared__ ushort sX[128 * 32];
    __shared__ ushort sL[128 * 32];
    __shared__ ushort sW[128 * 32];
    __shared__ ushort sG[128 * 32];
    const int t = threadIdx.x;
    const int lane = t & 63;
    const int w = t >> 6;
    const int wm = w >> 1, wn = w & 1;
    const int rowA = blockIdx.y * 128;   // M tile base
    const int rowB = blockIdx.x * 128;   // N tile base

    floatx4 acca[4][4], accm[4][4], accg[4][4];
    const floatx4 z = {0.f, 0.f, 0.f, 0.f};
#pragma unroll
    for (int i = 0; i < 4; i++)
#pragma unroll
        for (int j = 0; j < 4; j++) { acca[i][j] = z; accm[i][j] = z; accg[i][j] = z; }

    const int r0 = t >> 2;
    const int c8 = (t & 3) << 3;
    const ushort* gX0 = Xb + (size_t)(rowA + r0) * K_DIM + c8;
    const ushort* gX1 = gX0 + (size_t)64 * K_DIM;
    const ushort* gL0 = Lb + (size_t)(rowA + r0) * K_DIM + c8;
    const ushort* gL1 = gL0 + (size_t)64 * K_DIM;
    const ushort* gW0 = Wt + (size_t)(rowB + r0) * K_DIM + c8;
    const ushort* gW1 = gW0 + (size_t)64 * K_DIM;
    const ushort* gG0 = Gt + (size_t)(rowB + r0) * K_DIM + c8;
    const ushort* gG1 = gG0 + (size_t)64 * K_DIM;
    ushort* lX0 = sX + t * 8;
    ushort* lX1 = sX + (t + 256) * 8;
    ushort* lL0 = sL + t * 8;
    ushort* lL1 = sL + (t + 256) * 8;
    ushort* lW0 = sW + t * 8;
    ushort* lW1 = sW + (t + 256) * 8;
    ushort* lG0 = sG + t * 8;
    ushort* lG1 = sG + (t + 256) * 8;

    const int lr = lane & 15;
    const int lk = (lane >> 4) << 3;

    for (int k0 = 0; k0 < K_DIM; k0 += 32) {
        gld_lds16(gX0 + k0, lX0);
        gld_lds16(gX1 + k0, lX1);
        gld_lds16(gL0 + k0, lL0);
        gld_lds16(gL1 + k0, lL1);
        gld_lds16(gW0 + k0, lW0);
        gld_lds16(gW1 + k0, lW1);
        gld_lds16(gG0 + k0, lG0);
        gld_lds16(gG1 + k0, lG1);
        asm volatile("s_waitcnt vmcnt(0)" ::: "memory");
        __syncthreads();
        short8 bw[4], bg[4];
#pragma unroll
        for (int ni = 0; ni < 4; ni++) {
            bw[ni] = *(const short8*)(sW + (wn * 64 + ni * 16 + lr) * 32 + lk);
            bg[ni] = *(const short8*)(sG + (wn * 64 + ni * 16 + lr) * 32 + lk);
        }
#pragma unroll
        for (int mi = 0; mi < 4; mi++) {
            short8 ax = *(const short8*)(sX + (wm * 64 + mi * 16 + lr) * 32 + lk);
            short8 al = *(const short8*)(sL + (wm * 64 + mi * 16 + lr) * 32 + lk);
#pragma unroll
            for (int ni = 0; ni < 4; ni++) {
                acca[mi][ni] = __builtin_amdgcn_mfma_f32_16x16x32_bf16(ax, bw[ni], acca[mi][ni], 0, 0, 0);
                accm[mi][ni] = __builtin_amdgcn_mfma_f32_16x16x32_bf16(al, bw[ni], accm[mi][ni], 0, 0, 0);
                accg[mi][ni] = __builtin_amdgcn_mfma_f32_16x16x32_bf16(ax, bg[ni], accg[mi][ni], 0, 0, 0);
            }
        }
        __syncthreads();
    }

    const int rsub = (lane >> 4) << 2;
#pragma unroll
    for (int mi = 0; mi < 4; mi++)
#pragma unroll
        for (int ni = 0; ni < 4; ni++)
#pragma unroll
            for (int r = 0; r < 4; r++) {
                int row = rowA + wm * 64 + mi * 16 + rsub + r;
                int col = rowB + wn * 64 + ni * 16 + lr;
                float g = 1.f / (1.f + __expf(-accg[mi][ni][r]));
                float a = acca[mi][ni][r];
                float m = __expf(accm[mi][ni][r]);
                out[(size_t)row * N_DIM + col] = g * a + (1.f - g) * m;
            }
}

extern "C" void kernel_launch(void* const* d_in, const int* in_sizes, int n_in,
                              void* d_out, int out_size, void* d_ws, size_t ws_size,
                              hipStream_t stream) {
    const float* X  = (const float*)d_in[0];
    const float* Wh = (const float*)d_in[1];
    const float* Mh = (const float*)d_in[2];
    const float* Gf = (const float*)d_in[3];
    float* out = (float*)d_out;

    // workspace layout (bytes):
    //   Xb : B*K*2  = 33,554,432
    //   Lb : B*K*2  = 33,554,432
    //   Wt : N*K*2  =  8,388,608   (transposed: [n][k])
    //   Gt : N*K*2  =  8,388,608
    char* ws = (char*)d_ws;
    ushort* Xb = (ushort*)(ws);
    ushort* Lb = (ushort*)(ws + (size_t)B_DIM * K_DIM * 2);
    ushort* Wt = (ushort*)(ws + (size_t)B_DIM * K_DIM * 4);
    ushort* Gt = (ushort*)(ws + (size_t)B_DIM * K_DIM * 4 + (size_t)N_DIM * K_DIM * 2);

    prep_x<<<dim3((B_DIM * K_DIM) / (256 * 4)), dim3(256), 0, stream>>>(
        (const float4*)X, Xb, Lb);

    prep_wg<<<dim3(N_DIM / 32, K_DIM / 32), dim3(32, 8), 0, stream>>>(Wh, Mh, Gf, Wt, Gt);

    gemm_fused<<<dim3(N_DIM / 128, B_DIM / 128), dim3(256), 0, stream>>>(Xb, Lb, Wt, Gt, out);
}

// Round 4
// 359.155 us; speedup vs baseline: 1.4401x; 1.4401x over previous
//
#include <hip/hip_runtime.h>
#include <stdint.h>

typedef __attribute__((ext_vector_type(8))) short short8;
typedef __attribute__((ext_vector_type(4))) float floatx4;

#define B_DIM 8192
#define K_DIM 2048
#define N_DIM 2048

// round-to-nearest-even fp32 -> bf16
__device__ __forceinline__ unsigned short f2bf(float f) {
    union { float f; unsigned u; } v; v.f = f;
    unsigned r = v.u + 0x7fffu + ((v.u >> 16) & 1u);
    return (unsigned short)(r >> 16);
}

__device__ __forceinline__ void gld_lds16(const void* g, void* l) {
    __builtin_amdgcn_global_load_lds(
        (const __attribute__((address_space(1))) void*)g,
        (__attribute__((address_space(3))) void*)l, 16, 0, 0);
}

// ---------------- prepass 1: X -> Xb (bf16), Lb = bf16(log(|x|+eps)) ----------------
__global__ __launch_bounds__(256) void prep_x(const float4* __restrict__ X4,
                                              ushort* __restrict__ Xb,
                                              ushort* __restrict__ Lb) {
    int i = blockIdx.x * 256 + threadIdx.x;
    float4 v = X4[i];
    ushort4 xb, lb;
    xb.x = f2bf(v.x); xb.y = f2bf(v.y); xb.z = f2bf(v.z); xb.w = f2bf(v.w);
    lb.x = f2bf(__logf(fabsf(v.x) + 1e-7f));
    lb.y = f2bf(__logf(fabsf(v.y) + 1e-7f));
    lb.z = f2bf(__logf(fabsf(v.z) + 1e-7f));
    lb.w = f2bf(__logf(fabsf(v.w) + 1e-7f));
    *(ushort4*)(Xb + (size_t)i * 4) = xb;
    *(ushort4*)(Lb + (size_t)i * 4) = lb;
}

// ---------------- prepass 2: Wt[n][k] = bf16(tanh(Wh)*sigmoid(Mh)), Gt[n][k] = bf16(gate) ----
__global__ __launch_bounds__(256) void prep_wg(const float* __restrict__ Wh,
                                               const float* __restrict__ Mh,
                                               const float* __restrict__ Gf,
                                               ushort* __restrict__ Wt,
                                               ushort* __restrict__ Gt) {
    __shared__ float tw[32][33];
    __shared__ float tg[32][33];
    const int k0 = blockIdx.y * 32, n0 = blockIdx.x * 32;
    const int tx = threadIdx.x, ty = threadIdx.y;  // 32 x 8
#pragma unroll
    for (int i = 0; i < 4; i++) {
        int k = k0 + ty + i * 8;
        int n = n0 + tx;
        size_t idx = (size_t)k * N_DIM + n;
        float wh = Wh[idx], mh = Mh[idx];
        tw[ty + i * 8][tx] = tanhf(wh) * (1.f / (1.f + __expf(-mh)));
        tg[ty + i * 8][tx] = Gf[idx];
    }
    __syncthreads();
#pragma unroll
    for (int i = 0; i < 4; i++) {
        int n = n0 + ty + i * 8;
        int k = k0 + tx;
        Wt[(size_t)n * K_DIM + k] = f2bf(tw[tx][ty + i * 8]);
        Gt[(size_t)n * K_DIM + k] = f2bf(tg[tx][ty + i * 8]);
    }
}

// ---------------- fused GEMM: a = Xb@Wt^T, lm = Lb@Wt^T, gl = Xb@Gt^T ----------------
// out = sigmoid(gl)*a + (1-sigmoid(gl))*exp(lm)
// 128x128 block tile, 4 waves (2x2), 64x64 per wave per acc set, BK=32.
// __launch_bounds__(256, 2): force <=256 unified regs -> 8 waves/CU, 2 blocks/CU.
// LDS: ONE shared object (cross-section pointer offsets are only legal within
// a single object — the round-3 four-array version read garbage across array
// boundaries and produced NaN).
__global__ __launch_bounds__(256, 2) void gemm_fused(const ushort* __restrict__ Xb,
                                                     const ushort* __restrict__ Lb,
                                                     const ushort* __restrict__ Wt,
                                                     const ushort* __restrict__ Gt,
                                                     float* __restrict__ out) {
    __shared__ ushort smem[4 * 128 * 32];   // [sX | sL | sW | sG]
    ushort* sX = smem;
    ushort* sL = smem + 1 * 128 * 32;
    ushort* sW = smem + 2 * 128 * 32;
    ushort* sG = smem + 3 * 128 * 32;

    const int t = threadIdx.x;
    const int lane = t & 63;
    const int w = t >> 6;
    const int wm = w >> 1, wn = w & 1;
    const int rowA = blockIdx.y * 128;   // M tile base
    const int rowB = blockIdx.x * 128;   // N tile base

    floatx4 acca[4][4], accm[4][4], accg[4][4];
    const floatx4 z = {0.f, 0.f, 0.f, 0.f};
#pragma unroll
    for (int i = 0; i < 4; i++)
#pragma unroll
        for (int j = 0; j < 4; j++) { acca[i][j] = z; accm[i][j] = z; accg[i][j] = z; }

    const int r0 = t >> 2;            // 0..63
    const int c8 = (t & 3) << 3;      // 0,8,16,24
    const int aoff0 = (rowA + r0) * K_DIM + c8;
    const int aoff1 = aoff0 + 64 * K_DIM;
    const int boff0 = (rowB + r0) * K_DIM + c8;
    const int boff1 = boff0 + 64 * K_DIM;

    // LDS fragment read bases: one lane-dependent address per side; all
    // ds_read_b128 use constant offsets from these (within the SAME object).
    const int lr = lane & 15;
    const int lk = (lane >> 4) << 3;
    const ushort* rdA = sX + (wm * 64 + lr) * 32 + lk;   // +128*32 -> sL section
    const ushort* rdB = sW + (wn * 64 + lr) * 32 + lk;   // +128*32 -> sG section

    for (int k0 = 0; k0 < K_DIM; k0 += 32) {
        gld_lds16(Xb + aoff0 + k0, sX + t * 8);
        gld_lds16(Xb + aoff1 + k0, sX + (t + 256) * 8);
        gld_lds16(Lb + aoff0 + k0, sL + t * 8);
        gld_lds16(Lb + aoff1 + k0, sL + (t + 256) * 8);
        gld_lds16(Wt + boff0 + k0, sW + t * 8);
        gld_lds16(Wt + boff1 + k0, sW + (t + 256) * 8);
        gld_lds16(Gt + boff0 + k0, sG + t * 8);
        gld_lds16(Gt + boff1 + k0, sG + (t + 256) * 8);
        asm volatile("s_waitcnt vmcnt(0)" ::: "memory");
        __syncthreads();
        short8 bw[4], bg[4];
#pragma unroll
        for (int ni = 0; ni < 4; ni++) {
            bw[ni] = *(const short8*)(rdB + ni * 16 * 32);
            bg[ni] = *(const short8*)(rdB + (128 * 32) + ni * 16 * 32);
        }
#pragma unroll
        for (int mi = 0; mi < 4; mi++) {
            short8 ax = *(const short8*)(rdA + mi * 16 * 32);
            short8 al = *(const short8*)(rdA + (128 * 32) + mi * 16 * 32);
#pragma unroll
            for (int ni = 0; ni < 4; ni++) {
                acca[mi][ni] = __builtin_amdgcn_mfma_f32_16x16x32_bf16(ax, bw[ni], acca[mi][ni], 0, 0, 0);
                accm[mi][ni] = __builtin_amdgcn_mfma_f32_16x16x32_bf16(al, bw[ni], accm[mi][ni], 0, 0, 0);
                accg[mi][ni] = __builtin_amdgcn_mfma_f32_16x16x32_bf16(ax, bg[ni], accg[mi][ni], 0, 0, 0);
            }
        }
        __syncthreads();
    }

    const int rsub = (lane >> 4) << 2;
#pragma unroll
    for (int mi = 0; mi < 4; mi++)
#pragma unroll
        for (int ni = 0; ni < 4; ni++)
#pragma unroll
            for (int r = 0; r < 4; r++) {
                int row = rowA + wm * 64 + mi * 16 + rsub + r;
                int col = rowB + wn * 64 + ni * 16 + lr;
                float g = 1.f / (1.f + __expf(-accg[mi][ni][r]));
                float a = acca[mi][ni][r];
                float m = __expf(accm[mi][ni][r]);
                out[(size_t)row * N_DIM + col] = g * a + (1.f - g) * m;
            }
}

extern "C" void kernel_launch(void* const* d_in, const int* in_sizes, int n_in,
                              void* d_out, int out_size, void* d_ws, size_t ws_size,
                              hipStream_t stream) {
    const float* X  = (const float*)d_in[0];
    const float* Wh = (const float*)d_in[1];
    const float* Mh = (const float*)d_in[2];
    const float* Gf = (const float*)d_in[3];
    float* out = (float*)d_out;

    // workspace layout (bytes):
    //   Xb : B*K*2  = 33,554,432
    //   Lb : B*K*2  = 33,554,432
    //   Wt : N*K*2  =  8,388,608   (transposed: [n][k])
    //   Gt : N*K*2  =  8,388,608
    char* ws = (char*)d_ws;
    ushort* Xb = (ushort*)(ws);
    ushort* Lb = (ushort*)(ws + (size_t)B_DIM * K_DIM * 2);
    ushort* Wt = (ushort*)(ws + (size_t)B_DIM * K_DIM * 4);
    ushort* Gt = (ushort*)(ws + (size_t)B_DIM * K_DIM * 4 + (size_t)N_DIM * K_DIM * 2);

    prep_x<<<dim3((B_DIM * K_DIM) / (256 * 4)), dim3(256), 0, stream>>>(
        (const float4*)X, Xb, Lb);

    prep_wg<<<dim3(N_DIM / 32, K_DIM / 32), dim3(32, 8), 0, stream>>>(Wh, Mh, Gf, Wt, Gt);

    gemm_fused<<<dim3(N_DIM / 128, B_DIM / 128), dim3(256), 0, stream>>>(Xb, Lb, Wt, Gt, out);
}